// Round 1
// baseline (159.690 us; speedup 1.0000x reference)
//
#include <hip/hip_runtime.h>
#include <math.h>

// Problem shapes (fixed by setup_inputs): B=64, N=100, A=8732.
// Outputs (concatenated flat, all written as float32):
//   [0, B*A)          encoded_labels (int values as float)
//   [B*A, 5*B*A)      encoded boxes (B, A, 4)
//   [5*B*A, 6*B*A)    pos_mask (0.0 / 1.0)

#define EPS_F 1e-6f

// ---------------------------------------------------------------------------
// Kernel 1: column argmax — for each (b, n), argmax over anchors a of IoU,
// with np.argmax first-occurrence tie-break (max val, then lowest a).
// One block per (b, n); 256 threads stride over the 8732 anchors.
// ---------------------------------------------------------------------------
__global__ void col_argmax_kernel(const float4* __restrict__ gt_boxes,     // B*N (xyxy)
                                  const float4* __restrict__ anchors_xyxy, // A
                                  int* __restrict__ gt_anchors_idx,        // B*N
                                  int A, int N) {
    const int n = blockIdx.x;
    const int b = blockIdx.y;
    const int tid = threadIdx.x;

    const float4 g = gt_boxes[b * N + n];
    const float area_g = (g.z - g.x) * (g.w - g.y);

    float bv = -1.0f;
    int bi = 0x7fffffff;
    for (int a = tid; a < A; a += blockDim.x) {
        float4 an = anchors_xyxy[a];
        float ltx = fmaxf(an.x, g.x);
        float lty = fmaxf(an.y, g.y);
        float rbx = fminf(an.z, g.z);
        float rby = fminf(an.w, g.w);
        float w = fmaxf(rbx - ltx, 0.0f);
        float h = fmaxf(rby - lty, 0.0f);
        float inter = w * h;
        float area_a = (an.z - an.x) * (an.w - an.y);
        float iou = inter / (area_a + area_g - inter);
        // first-occurrence argmax: strictly greater, or equal with lower index
        if (iou > bv || (iou == bv && a < bi)) { bv = iou; bi = a; }
    }

    __shared__ float sval[256];
    __shared__ int   sidx[256];
    sval[tid] = bv;
    sidx[tid] = bi;
    __syncthreads();
    for (int s = 128; s > 0; s >>= 1) {
        if (tid < s) {
            float v2 = sval[tid + s];
            int   i2 = sidx[tid + s];
            if (v2 > sval[tid] || (v2 == sval[tid] && i2 < sidx[tid])) {
                sval[tid] = v2;
                sidx[tid] = i2;
            }
        }
        __syncthreads();
    }
    if (tid == 0) gt_anchors_idx[b * N + n] = sidx[0];
}

// ---------------------------------------------------------------------------
// Kernel 2: per-anchor row argmax over n (first-occurrence), apply the
// gt->anchor override (last n wins on duplicates, matching numpy fancy
// assignment), then encode and write all three outputs.
// Grid: (ceil(A/256), B), 256 threads.
// ---------------------------------------------------------------------------
__global__ void encode_kernel(const int* __restrict__ gt_labels,          // B*N
                              const float4* __restrict__ gt_boxes,        // B*N (xyxy)
                              const float4* __restrict__ anchors_cxcywh,  // A
                              const float4* __restrict__ anchors_xyxy,    // A
                              const int* __restrict__ gt_anchors_idx,     // B*N
                              float* __restrict__ out,
                              int A, int N, int B) {
    const int b = blockIdx.y;
    const int tid = threadIdx.x;
    const int a = blockIdx.x * blockDim.x + tid;

    __shared__ float4 sg[128];   // gt boxes (xyxy)
    __shared__ int    sgi[128];  // gt_anchors_idx
    __shared__ int    slab[128]; // gt labels
    if (tid < N) {
        sg[tid]   = gt_boxes[b * N + tid];
        sgi[tid]  = gt_anchors_idx[b * N + tid];
        slab[tid] = gt_labels[b * N + tid];
    }
    __syncthreads();

    if (a >= A) return;

    const float4 axy = anchors_xyxy[a];
    const float area_a = (axy.z - axy.x) * (axy.w - axy.y);

    float bv = -1.0f;  // iou >= 0, so n=0 always taken first
    int bi = 0;
    int ovr = -1;
    for (int n = 0; n < N; n++) {
        float4 g = sg[n];
        float ltx = fmaxf(axy.x, g.x);
        float lty = fmaxf(axy.y, g.y);
        float rbx = fminf(axy.z, g.z);
        float rby = fminf(axy.w, g.w);
        float w = fmaxf(rbx - ltx, 0.0f);
        float h = fmaxf(rby - lty, 0.0f);
        float inter = w * h;
        float area_g = (g.z - g.x) * (g.w - g.y);
        float iou = inter / (area_a + area_g - inter);
        if (iou > bv) { bv = iou; bi = n; }   // strict > keeps first max
        if (sgi[n] == a) ovr = n;             // ascending scan: last n wins
    }

    float val;
    int idx;
    if (ovr >= 0) { idx = ovr; val = 2.0f; }
    else          { idx = bi;  val = bv; }
    const bool pos = val > 0.5f;

    // matched gt box -> cxcywh
    const float4 g = sg[idx];
    const float gcx = (g.x + g.z) * 0.5f;
    const float gcy = (g.y + g.w) * 0.5f;
    const float gw  = g.z - g.x;
    const float gh  = g.w - g.y;

    const float4 anc = anchors_cxcywh[a];
    const float ecx = (gcx - anc.x) / anc.z;
    const float ecy = (gcy - anc.y) / anc.w;
    const float ew  = logf((gw + EPS_F) / (anc.z + EPS_F));
    const float eh  = logf((gh + EPS_F) / (anc.w + EPS_F));

    const long long BA = (long long)B * A;
    const long long base = (long long)b * A + a;

    out[base] = pos ? (float)slab[idx] : 0.0f;          // encoded_labels
    float4* o1 = (float4*)(out + BA);
    o1[base] = make_float4(ecx, ecy, ew, eh);           // encoded (B, A, 4)
    out[5 * BA + base] = pos ? 1.0f : 0.0f;             // pos_mask
}

extern "C" void kernel_launch(void* const* d_in, const int* in_sizes, int n_in,
                              void* d_out, int out_size, void* d_ws, size_t ws_size,
                              hipStream_t stream) {
    const int*    gt_labels     = (const int*)d_in[0];
    const float4* gt_boxes      = (const float4*)d_in[1];
    const float4* anchors_cxcy  = (const float4*)d_in[2];
    const float4* anchors_xyxy  = (const float4*)d_in[3];
    float*        out           = (float*)d_out;

    const int B = 64;
    const int N = in_sizes[0] / B;       // 100
    const int A = in_sizes[2] / 4;       // 8732

    int* gt_anchors_idx = (int*)d_ws;    // B*N ints

    dim3 grid1(N, B);
    col_argmax_kernel<<<grid1, 256, 0, stream>>>(gt_boxes, anchors_xyxy,
                                                 gt_anchors_idx, A, N);

    dim3 grid2((A + 255) / 256, B);
    encode_kernel<<<grid2, 256, 0, stream>>>(gt_labels, gt_boxes, anchors_cxcy,
                                             anchors_xyxy, gt_anchors_idx,
                                             out, A, N, B);
}

// Round 5
// 153.980 us; speedup vs baseline: 1.0371x; 1.0371x over previous
//
#include <hip/hip_runtime.h>
#include <math.h>

// CRITICAL: ban FMA contraction file-wide. HIP default is
// -ffp-contract=fast-honor-pragmas; contraction turns
// `area_a + area_g - inter` into fma(-w,h,...) (1-ulp iou shifts) which
// flips near-tie argmaxes vs the correctly-rounded numpy reference
// (rounds 2-4 all failed with identical label absmax 69 from this).
#pragma clang fp contract(off)

// Shapes fixed by setup_inputs: B=64, N=100, A=8732.
// Output layout (float32, flat): [0,BA) labels | [BA,5BA) boxes | [5BA,6BA) mask
// ws: gt_anchors_idx int[B*N] = 25,600 bytes (round-1 proven size).
//
// ROUND-1 PROVEN LOGIC:
//  - exact IEEE f32 IoU expression (bitwise == numpy) — no contraction
//  - column argmax: max iou, tie -> lowest anchor idx (np first occurrence)
//  - row argmax: sequential n, strict > (np first occurrence)
//  - override: ascending scan, last n wins (np fancy-assignment)

#define AA 8732
#define NN 100
#define BB 64
#define NPB 4          // columns (gt boxes) per block in kernel 1
#define EPS_F 1e-6f

// ---------------------------------------------------------------------------
// Kernel 1: column argmax — for each (b, n), argmax over anchors of IoU.
// NPB columns per block: each anchor load feeds NPB independent IoU/div
// chains (ILP) and cuts per-block anchor traffic NPB-fold.
// ---------------------------------------------------------------------------
__global__ __launch_bounds__(256) void col_argmax_kernel(
        const float4* __restrict__ gt_boxes,     // B*N xyxy
        const float4* __restrict__ anchors_xyxy, // A
        int* __restrict__ gt_anchors_idx)        // B*N
{
    const int b  = blockIdx.y;
    const int n0 = blockIdx.x * NPB;   // 25 groups of 4 = 100
    const int tid = threadIdx.x;

    float4 g[NPB];
    float  area_g[NPB];
    #pragma unroll
    for (int j = 0; j < NPB; j++) {
        g[j] = gt_boxes[b * NN + n0 + j];
        area_g[j] = (g[j].z - g[j].x) * (g[j].w - g[j].y);
    }

    float bv[NPB];
    int   bi[NPB];
    #pragma unroll
    for (int j = 0; j < NPB; j++) { bv[j] = -1.0f; bi[j] = 0x7fffffff; }

    #pragma unroll 2
    for (int a = tid; a < AA; a += 256) {
        float4 an = anchors_xyxy[a];
        float area_a = (an.z - an.x) * (an.w - an.y);
        #pragma unroll
        for (int j = 0; j < NPB; j++) {
            float ltx = fmaxf(an.x, g[j].x);
            float lty = fmaxf(an.y, g[j].y);
            float rbx = fminf(an.z, g[j].z);
            float rby = fminf(an.w, g[j].w);
            float w = fmaxf(rbx - ltx, 0.0f);
            float h = fmaxf(rby - lty, 0.0f);
            float inter = w * h;
            float iou = inter / (area_a + area_g[j] - inter); // exact IEEE == numpy
            if (iou > bv[j] || (iou == bv[j] && a < bi[j])) { bv[j] = iou; bi[j] = a; }
        }
    }

    __shared__ float sval[NPB][256];
    __shared__ int   sidx[NPB][256];
    #pragma unroll
    for (int j = 0; j < NPB; j++) { sval[j][tid] = bv[j]; sidx[j][tid] = bi[j]; }
    __syncthreads();
    for (int s = 128; s > 0; s >>= 1) {
        if (tid < s) {
            #pragma unroll
            for (int j = 0; j < NPB; j++) {
                float v2 = sval[j][tid + s];
                int   i2 = sidx[j][tid + s];
                if (v2 > sval[j][tid] || (v2 == sval[j][tid] && i2 < sidx[j][tid])) {
                    sval[j][tid] = v2;
                    sidx[j][tid] = i2;
                }
            }
        }
        __syncthreads();
    }
    if (tid < NPB) gt_anchors_idx[b * NN + n0 + tid] = sidx[tid][0];
}

// ---------------------------------------------------------------------------
// Kernel 2: per-anchor row argmax over n (first occurrence), override via
// ascending sgi scan (last n wins), then encode + write all outputs.
// ---------------------------------------------------------------------------
__global__ __launch_bounds__(256) void encode_kernel(
        const int* __restrict__ gt_labels,          // B*N
        const float4* __restrict__ gt_boxes,        // B*N xyxy
        const float4* __restrict__ anchors_cxcywh,  // A
        const float4* __restrict__ anchors_xyxy,    // A
        const int* __restrict__ gt_anchors_idx,     // B*N
        float* __restrict__ out)
{
    const int b = blockIdx.y;
    const int tid = threadIdx.x;
    const int a = blockIdx.x * 256 + tid;

    __shared__ float4 sg[NN];
    __shared__ float  sarea[NN];
    __shared__ int    sgi[NN];
    __shared__ int    slab[NN];
    if (tid < NN) {
        float4 gg = gt_boxes[b * NN + tid];
        sg[tid]    = gg;
        sarea[tid] = (gg.z - gg.x) * (gg.w - gg.y);
        sgi[tid]   = gt_anchors_idx[b * NN + tid];
        slab[tid]  = gt_labels[b * NN + tid];
    }
    __syncthreads();

    if (a >= AA) return;

    const float4 axy = anchors_xyxy[a];
    const float area_a = (axy.z - axy.x) * (axy.w - axy.y);

    float bv = -1.0f;  // iou >= 0, so n=0 always taken first
    int bi = 0;
    int ovr = -1;
    #pragma unroll 4
    for (int n = 0; n < NN; n++) {
        float4 gg = sg[n];
        float area_g = sarea[n];
        float ltx = fmaxf(axy.x, gg.x);
        float lty = fmaxf(axy.y, gg.y);
        float rbx = fminf(axy.z, gg.z);
        float rby = fminf(axy.w, gg.w);
        float w = fmaxf(rbx - ltx, 0.0f);
        float h = fmaxf(rby - lty, 0.0f);
        float inter = w * h;
        float iou = inter / (area_a + area_g - inter);  // exact IEEE == numpy
        if (iou > bv) { bv = iou; bi = n; }   // strict > keeps first max
        if (sgi[n] == a) ovr = n;             // ascending scan: last n wins
    }

    float val;
    int idx;
    if (ovr >= 0) { idx = ovr; val = 2.0f; }
    else          { idx = bi;  val = bv; }
    const bool pos = val > 0.5f;

    const float4 gg = sg[idx];
    const float gcx = (gg.x + gg.z) * 0.5f;
    const float gcy = (gg.y + gg.w) * 0.5f;
    const float gw  = gg.z - gg.x;
    const float gh  = gg.w - gg.y;

    const float4 anc = anchors_cxcywh[a];
    const float ecx = (gcx - anc.x) / anc.z;
    const float ecy = (gcy - anc.y) / anc.w;
    const float ew  = logf((gw + EPS_F) / (anc.z + EPS_F));
    const float eh  = logf((gh + EPS_F) / (anc.w + EPS_F));

    const size_t BA = (size_t)BB * AA;
    const size_t base = (size_t)b * AA + a;

    out[base] = pos ? (float)slab[idx] : 0.0f;                   // labels
    ((float4*)(out + BA))[base] = make_float4(ecx, ecy, ew, eh); // boxes
    out[5 * BA + base] = pos ? 1.0f : 0.0f;                      // mask
}

extern "C" void kernel_launch(void* const* d_in, const int* in_sizes, int n_in,
                              void* d_out, int out_size, void* d_ws, size_t ws_size,
                              hipStream_t stream) {
    const int*    gt_labels    = (const int*)d_in[0];
    const float4* gt_boxes     = (const float4*)d_in[1];
    const float4* anchors_cxcy = (const float4*)d_in[2];
    const float4* anchors_xyxy = (const float4*)d_in[3];
    float* out = (float*)d_out;

    int* gt_anchors_idx = (int*)d_ws;   // B*N ints = 25,600 B (round-1 proven)

    dim3 grid1(NN / NPB, BB);           // (25, 64)
    col_argmax_kernel<<<grid1, 256, 0, stream>>>(gt_boxes, anchors_xyxy,
                                                 gt_anchors_idx);

    dim3 grid2((AA + 255) / 256, BB);   // (35, 64)
    encode_kernel<<<grid2, 256, 0, stream>>>(gt_labels, gt_boxes, anchors_cxcy,
                                             anchors_xyxy, gt_anchors_idx, out);
}